// Round 13
// baseline (453.899 us; speedup 1.0000x reference)
//
#include <hip/hip_runtime.h>
#include <cmath>

#define NL 16
#define NPAIR 7          // levels 0..6 have dense f32 z-pair tables
#define TABLE_SIZE (1u << 19)
#define TABLE_MASK (TABLE_SIZE - 1u)
#define P1 2654435761u
#define P2 805459861u

typedef float f2v __attribute__((ext_vector_type(2)));
typedef float f4v __attribute__((ext_vector_type(4)));
typedef unsigned int u32;

struct Params {
  float g[NL];
  int R[NPAIR];
  u32 off[NPAIR];   // pair-table offsets, in 16B entries
  u32 nE[NPAIR];
  u32 totE;
};

struct Corners { u32 idx[8]; float wx, wy, wz; };

__device__ __forceinline__ Corners make_corners(
    float g, float px, float py, float pz, float qx, float qy, float qz)
{
  Corners c;
  const float fx = floorf((qx + 1.f) / g);
  const float fy = floorf((qy + 1.f) / g);
  const float fz = floorf((qz + 1.f) / g);
  c.wx = (px - (fx * g - 1.f)) / g;
  c.wy = (py - (fy * g - 1.f)) / g;
  c.wz = (pz - (fz * g - 1.f)) / g;
  const u32 hx0 = (u32)(int)fx;
  const u32 hy0 = (u32)(int)fy * P1;
  const u32 hz0 = (u32)(int)fz * P2;
  const u32 hx1 = hx0 + 1u;
  const u32 hy1 = hy0 + P1;
  const u32 hz1 = hz0 + P2;
  c.idx[0] = (hx0 ^ hy0 ^ hz0) & TABLE_MASK;
  c.idx[1] = (hx0 ^ hy0 ^ hz1) & TABLE_MASK;
  c.idx[2] = (hx0 ^ hy1 ^ hz0) & TABLE_MASK;
  c.idx[3] = (hx0 ^ hy1 ^ hz1) & TABLE_MASK;
  c.idx[4] = (hx1 ^ hy0 ^ hz0) & TABLE_MASK;
  c.idx[5] = (hx1 ^ hy0 ^ hz1) & TABLE_MASK;
  c.idx[6] = (hx1 ^ hy1 ^ hz0) & TABLE_MASK;
  c.idx[7] = (hx1 ^ hy1 ^ hz1) & TABLE_MASK;
  return c;
}

__device__ __forceinline__ f2v trilerp8(const f2v e[8], float wx, float wy, float wz) {
  const float ux = 1.f - wx;
  const f2v a00 = e[0] * ux + e[4] * wx;
  const f2v a01 = e[1] * ux + e[5] * wx;
  const f2v a10 = e[2] * ux + e[6] * wx;
  const f2v a11 = e[3] * ux + e[7] * wx;
  const float uy = 1.f - wy;
  const f2v b0 = a00 * uy + a10 * wy;
  const f2v b1 = a01 * uy + a11 * wy;
  const float uz = 1.f - wz;
  return b0 * uz + b1 * wz;
}

// ---- hashed-level eval via x-pair blocks (round-7 validated) ----
// PRIMES[0]==1 => for even bx, h(bx+1)=h(bx)^1: both x-corners in one 16B block.
__device__ __forceinline__ f2v xpair_eval(
    const f4v* __restrict__ tab4, float g,
    float px, float py, float pz, float qx, float qy, float qz)
{
  const float fx = floorf((qx + 1.f) / g);
  const float fy = floorf((qy + 1.f) / g);
  const float fz = floorf((qz + 1.f) / g);
  const float wx = (px - (fx * g - 1.f)) / g;
  const float wy = (py - (fy * g - 1.f)) / g;
  const float wz = (pz - (fz * g - 1.f)) / g;
  const u32 bx = (u32)(int)fx;
  const u32 y0 = (u32)(int)fy * P1, y1 = y0 + P1;
  const u32 z0 = (u32)(int)fz * P2, z1 = z0 + P2;
  u32 hA[4], hB[4];
  const u32 w00 = y0 ^ z0, w01 = y0 ^ z1, w10 = y1 ^ z0, w11 = y1 ^ z1;
  hA[0] = (bx ^ w00) & TABLE_MASK;  hB[0] = ((bx + 1u) ^ w00) & TABLE_MASK;
  hA[1] = (bx ^ w01) & TABLE_MASK;  hB[1] = ((bx + 1u) ^ w01) & TABLE_MASK;
  hA[2] = (bx ^ w10) & TABLE_MASK;  hB[2] = ((bx + 1u) ^ w10) & TABLE_MASK;
  hA[3] = (bx ^ w11) & TABLE_MASK;  hB[3] = ((bx + 1u) ^ w11) & TABLE_MASK;

  f4v BA[4], BB[4];
#pragma unroll
  for (int c = 0; c < 4; ++c) BA[c] = tab4[hA[c] >> 1];
#pragma unroll
  for (int c = 0; c < 4; ++c) BB[c] = BA[c];
  if (bx & 1u) {                       // divergent: only odd-bx lanes load
#pragma unroll
    for (int c = 0; c < 4; ++c) BB[c] = tab4[hB[c] >> 1];
  }
  f2v e[8];
#pragma unroll
  for (int c = 0; c < 4; ++c) {
    const bool sA = (hA[c] & 1u) != 0u;
    const bool sB = (hB[c] & 1u) != 0u;
    e[c][0]     = sA ? BA[c][2] : BA[c][0];
    e[c][1]     = sA ? BA[c][3] : BA[c][1];
    e[4 + c][0] = sB ? BB[c][2] : BB[c][0];
    e[4 + c][1] = sB ? BB[c][3] : BB[c][1];
  }
  return trilerp8(e, wx, wy, wz);
}

// dense pair-table eval: 4 aligned 16B loads (round-4 validated)
__device__ __forceinline__ f2v pair_eval(
    const f4v* __restrict__ pt, int R, float g,
    float px, float py, float pz, float qx, float qy, float qz)
{
  const float fx = floorf((qx + 1.f) / g);
  const float fy = floorf((qy + 1.f) / g);
  const float fz = floorf((qz + 1.f) / g);
  const float wx = (px - (fx * g - 1.f)) / g;
  const float wy = (py - (fy * g - 1.f)) / g;
  const float wz = (pz - (fz * g - 1.f)) / g;
  const int bx = (int)fx, by = (int)fy, bz = (int)fz;
  const int s = R + 1;
  const int base = (bx * (R + 2) + by) * s + bz;
  const f4v p00 = pt[base];
  const f4v p01 = pt[base + s];
  const f4v p10 = pt[base + (R + 2) * s];
  const f4v p11 = pt[base + (R + 3) * s];
  const float uz = 1.f - wz;
  const f2v a00 = { p00[0] * uz + p00[2] * wz, p00[1] * uz + p00[3] * wz };
  const f2v a01 = { p01[0] * uz + p01[2] * wz, p01[1] * uz + p01[3] * wz };
  const f2v a10 = { p10[0] * uz + p10[2] * wz, p10[1] * uz + p10[3] * wz };
  const f2v a11 = { p11[0] * uz + p11[2] * wz, p11[1] * uz + p11[3] * wz };
  const float uy = 1.f - wy;
  const f2v b0 = a00 * uy + a01 * wy;
  const f2v b1 = a10 * uy + a11 * wy;
  const float ux = 1.f - wx;
  return b0 * ux + b1 * wx;
}

// ---------- build dense z-pair tables for levels 0..6 (round-4 validated) ----------
__global__ __launch_bounds__(256) void rehash_kernel(
    const float* __restrict__ tables, f4v* __restrict__ pt, Params P)
{
  u32 tid = blockIdx.x * 256 + threadIdx.x;
  if (tid >= P.totE) return;
  int l = 0; u32 e = tid;
  while (e >= P.nE[l]) { e -= P.nE[l]; ++l; }
  const u32 R = (u32)P.R[l];
  const u32 vz = e % (R + 1u);
  const u32 t2 = e / (R + 1u);
  const u32 vy = t2 % (R + 2u);
  const u32 vx = t2 / (R + 2u);
  const f2v* tab = (const f2v*)tables + (size_t)l * TABLE_SIZE;
  const u32 h0 = (vx ^ (vy * P1) ^ (vz * P2)) & TABLE_MASK;
  const u32 h1 = (vx ^ (vy * P1) ^ ((vz + 1u) * P2)) & TABLE_MASK;
  const f2v a = tab[h0], b = tab[h1];
  const f4v o = { a[0], a[1], b[0], b[1] };
  pt[P.off[l] + e] = o;
}

// ---------- single-level pair pass (l5, l6), 2 pts/thread (round-4 validated) ----------
__global__ __launch_bounds__(256) void pair_pass_kernel(
    const float* __restrict__ xin, const f4v* __restrict__ pt,
    f2v* __restrict__ wsl, int npts, int strideT, int R, float g)
{
  const int n0 = blockIdx.x * 256 + threadIdx.x;
  const int n1 = n0 + strideT;
  const int c0 = n0 < npts ? n0 : npts - 1;
  const int c1 = n1 < npts ? n1 : npts - 1;
  const float px0 = xin[3 * c0 + 0], py0 = xin[3 * c0 + 1], pz0 = xin[3 * c0 + 2];
  const float px1 = xin[3 * c1 + 0], py1 = xin[3 * c1 + 1], pz1 = xin[3 * c1 + 2];
  const float qx0 = fminf(fmaxf(px0, -1.f), 1.f), qy0 = fminf(fmaxf(py0, -1.f), 1.f), qz0 = fminf(fmaxf(pz0, -1.f), 1.f);
  const float qx1 = fminf(fmaxf(px1, -1.f), 1.f), qy1 = fminf(fmaxf(py1, -1.f), 1.f), qz1 = fminf(fmaxf(pz1, -1.f), 1.f);
  const f2v r0 = pair_eval(pt, R, g, px0, py0, pz0, qx0, qy0, qz0);
  const f2v r1 = pair_eval(pt, R, g, px1, py1, pz1, qx1, qy1, qz1);
  if (n0 < npts) __builtin_nontemporal_store(r0, wsl + n0);
  if (n1 < npts) __builtin_nontemporal_store(r1, wsl + n1);
}

// ---------- hashed pass with x-pair blocks: one level, 4 pts/thread (round-7 validated) ----------
__global__ __launch_bounds__(256) void xpair_pass_kernel(
    const float* __restrict__ xin, const f4v* __restrict__ tab4,
    f2v* __restrict__ wsl, int npts, int strideT, float g)
{
  const int nb = blockIdx.x * 256 + threadIdx.x;
#pragma unroll
  for (int i = 0; i < 4; ++i) {
    const int n = nb + i * strideT;
    const int c = n < npts ? n : npts - 1;
    const float px = xin[3 * c + 0], py = xin[3 * c + 1], pz = xin[3 * c + 2];
    const float qx = fminf(fmaxf(px, -1.f), 1.f);
    const float qy = fminf(fmaxf(py, -1.f), 1.f);
    const float qz = fminf(fmaxf(pz, -1.f), 1.f);
    const f2v r = xpair_eval(tab4, g, px, py, pz, qx, qy, qz);
    if (n < npts) __builtin_nontemporal_store(r, wsl + n);
  }
}

// ---------- final: l0..l4 gathers (2.35MB tables, L2-resident) staged in 10.3KB LDS +
// l5..l15 read DIRECTLY from ws in transposed order (plain loads, FETCH-clean per r11/r12) ----------
__global__ __launch_bounds__(256) void final_kernel(
    const float* __restrict__ xin, const f4v* __restrict__ pt,
    const f2v* __restrict__ ws, float* __restrict__ out, int npts, Params P)
{
  __shared__ f2v lds5[5][257];
  const int t = threadIdx.x;
  const int base = blockIdx.x * 256;
  const int n = base + t;
  const int c = n < npts ? n : npts - 1;
  {
    const float px = xin[3 * c + 0], py = xin[3 * c + 1], pz = xin[3 * c + 2];
    const float qx = fminf(fmaxf(px, -1.f), 1.f);
    const float qy = fminf(fmaxf(py, -1.f), 1.f);
    const float qz = fminf(fmaxf(pz, -1.f), 1.f);
#pragma unroll
    for (int l = 0; l < 5; ++l)
      lds5[l][t] = pair_eval(pt + P.off[l], P.R[l], P.g[l], px, py, pz, qx, qy, qz);
  }
  __syncthreads();
  // lane's lp = t&7 is constant across k (256 ≡ 0 mod 8) -> static role per lane.
  // 8 lanes sharing lp read 8 consecutive points = 64B contiguous; adjacent 64B
  // of the same 128B line is read by the next wave in the same iteration -> L2 hit.
#pragma unroll
  for (int k = 0; k < 8; ++k) {
    const int j4 = t + 256 * k;
    const int p = j4 >> 3;
    const int lp = j4 & 7;
    if (base + p < npts) {
      f2v a, b;
      if (lp < 2) {
        a = lds5[2 * lp + 0][p];
        b = lds5[2 * lp + 1][p];
      } else if (lp == 2) {
        a = lds5[4][p];
        b = ws[(size_t)0 * npts + base + p];               // l5 = slab 0
      } else {
        a = ws[(size_t)(2 * lp - 5) * npts + base + p];    // l(2lp) = slab 2lp-5
        b = ws[(size_t)(2 * lp - 4) * npts + base + p];    // l(2lp+1)
      }
      const f4v v = { a[0], a[1], b[0], b[1] };
      __builtin_nontemporal_store(v, (f4v*)(out + (size_t)base * 32) + j4);
    }
  }
}

// ---------- fallback: fused single-pass (round-1 validated) ----------
__global__ __launch_bounds__(256) void hash_embed_fused_kernel(
    const float* __restrict__ xin, const float* __restrict__ tables,
    float* __restrict__ out, int npts, Params P)
{
  int n = blockIdx.x * blockDim.x + threadIdx.x;
  if (n >= npts) return;
  const float px = xin[3 * n + 0], py = xin[3 * n + 1], pz = xin[3 * n + 2];
  const float qx = fminf(fmaxf(px, -1.f), 1.f);
  const float qy = fminf(fmaxf(py, -1.f), 1.f);
  const float qz = fminf(fmaxf(pz, -1.f), 1.f);
  f2v acc[NL];
#pragma unroll
  for (int l = 0; l < NL; ++l) {
    const Corners c = make_corners(P.g[l], px, py, pz, qx, qy, qz);
    const f2v* tab = (const f2v*)tables + (size_t)l * TABLE_SIZE;
    f2v e[8];
#pragma unroll
    for (int j = 0; j < 8; ++j) e[j] = tab[c.idx[j]];
    acc[l] = trilerp8(e, c.wx, c.wy, c.wz);
  }
  f4v* o = (f4v*)(out + (size_t)n * 32);
#pragma unroll
  for (int i = 0; i < 8; ++i) {
    const f4v v = { acc[2 * i][0], acc[2 * i][1], acc[2 * i + 1][0], acc[2 * i + 1][1] };
    o[i] = v;
  }
}

extern "C" void kernel_launch(void* const* d_in, const int* in_sizes, int n_in,
                              void* d_out, int out_size, void* d_ws, size_t ws_size,
                              hipStream_t stream) {
  const float* x = (const float*)d_in[0];
  const float* tables = (const float*)d_in[1];
  float* out = (float*)d_out;
  const int npts = in_sizes[0] / 3;

  Params P;
  {
    const float b = expf((logf(512.0f) - logf(16.0f)) / 15.0f);
    u32 off = 0;
    for (int l = 0; l < NL; ++l) {
      const float r = floorf(16.0f * powf(b, (float)l));
      P.g[l] = 2.0f / r;
      if (l < NPAIR) {
        const int R = (int)r;
        P.R[l] = R;
        P.nE[l] = (u32)((R + 2) * (R + 2) * (R + 1));
        P.off[l] = off;
        off += P.nE[l];
      }
    }
    P.totE = off;   // ~566K entries = ~9.06 MB of f4v
  }

  // ws layout: [l5..l15 feature slabs: 11 * npts * 8B][z-pair tables: totE * 16B]
  const size_t slab_bytes = (size_t)11 * npts * sizeof(f2v);            // 88 MB
  const size_t pt_off = (slab_bytes + 255) & ~(size_t)255;
  const size_t need = pt_off + (size_t)P.totE * sizeof(f4v);            // ~97 MB

  if (ws_size >= need) {
    f2v* ws = (f2v*)d_ws;
    f4v* pt = (f4v*)((char*)d_ws + pt_off);

    hipLaunchKernelGGL(rehash_kernel, dim3((P.totE + 255) / 256), dim3(256), 0, stream,
                       tables, pt, P);

    const int grid2 = (npts + 511) / 512;
    const int stride2 = grid2 * 256;
    for (int l = 5; l < NPAIR; ++l)
      hipLaunchKernelGGL(pair_pass_kernel, dim3(grid2), dim3(256), 0, stream,
                         x, pt + P.off[l], ws + (size_t)(l - 5) * npts, npts, stride2,
                         P.R[l], P.g[l]);

    const int grid4 = (npts + 1023) / 1024;
    const int stride4 = grid4 * 256;
    for (int l = NPAIR; l < NL; ++l)
      hipLaunchKernelGGL(xpair_pass_kernel, dim3(grid4), dim3(256), 0, stream,
                         x, (const f4v*)((const f2v*)tables + (size_t)l * TABLE_SIZE),
                         ws + (size_t)(l - 5) * npts, npts, stride4, P.g[l]);

    const int grid = (npts + 255) / 256;
    hipLaunchKernelGGL(final_kernel, dim3(grid), dim3(256), 0, stream,
                       x, pt, ws, out, npts, P);
  } else {
    hipLaunchKernelGGL(hash_embed_fused_kernel, dim3((npts + 255) / 256), dim3(256), 0, stream,
                       x, tables, out, npts, P);
  }
}

// Round 14
// 441.252 us; speedup vs baseline: 1.0287x; 1.0287x over previous
//
#include <hip/hip_runtime.h>
#include <cmath>

#define NL 16
#define NPAIR 7          // levels 0..6 have dense f32 z-pair tables
#define TABLE_SIZE (1u << 19)
#define TABLE_MASK (TABLE_SIZE - 1u)
#define P1 2654435761u
#define P2 805459861u

typedef float f2v __attribute__((ext_vector_type(2)));
typedef float f4v __attribute__((ext_vector_type(4)));
typedef unsigned int u32;

struct Params {
  float g[NL];
  int R[NPAIR];
  u32 off[NPAIR];   // pair-table offsets, in 16B entries
  u32 nE[NPAIR];
  u32 totE;
};

struct Corners { u32 idx[8]; float wx, wy, wz; };

__device__ __forceinline__ Corners make_corners(
    float g, float px, float py, float pz, float qx, float qy, float qz)
{
  Corners c;
  const float fx = floorf((qx + 1.f) / g);
  const float fy = floorf((qy + 1.f) / g);
  const float fz = floorf((qz + 1.f) / g);
  c.wx = (px - (fx * g - 1.f)) / g;
  c.wy = (py - (fy * g - 1.f)) / g;
  c.wz = (pz - (fz * g - 1.f)) / g;
  const u32 hx0 = (u32)(int)fx;
  const u32 hy0 = (u32)(int)fy * P1;
  const u32 hz0 = (u32)(int)fz * P2;
  const u32 hx1 = hx0 + 1u;
  const u32 hy1 = hy0 + P1;
  const u32 hz1 = hz0 + P2;
  c.idx[0] = (hx0 ^ hy0 ^ hz0) & TABLE_MASK;
  c.idx[1] = (hx0 ^ hy0 ^ hz1) & TABLE_MASK;
  c.idx[2] = (hx0 ^ hy1 ^ hz0) & TABLE_MASK;
  c.idx[3] = (hx0 ^ hy1 ^ hz1) & TABLE_MASK;
  c.idx[4] = (hx1 ^ hy0 ^ hz0) & TABLE_MASK;
  c.idx[5] = (hx1 ^ hy0 ^ hz1) & TABLE_MASK;
  c.idx[6] = (hx1 ^ hy1 ^ hz0) & TABLE_MASK;
  c.idx[7] = (hx1 ^ hy1 ^ hz1) & TABLE_MASK;
  return c;
}

__device__ __forceinline__ f2v trilerp8(const f2v e[8], float wx, float wy, float wz) {
  const float ux = 1.f - wx;
  const f2v a00 = e[0] * ux + e[4] * wx;
  const f2v a01 = e[1] * ux + e[5] * wx;
  const f2v a10 = e[2] * ux + e[6] * wx;
  const f2v a11 = e[3] * ux + e[7] * wx;
  const float uy = 1.f - wy;
  const f2v b0 = a00 * uy + a10 * wy;
  const f2v b1 = a01 * uy + a11 * wy;
  const float uz = 1.f - wz;
  return b0 * uz + b1 * wz;
}

// ---- hashed-level eval via x-pair blocks (round-7 validated) ----
// PRIMES[0]==1 => for even bx, h(bx+1)=h(bx)^1: both x-corners in one 16B block.
__device__ __forceinline__ f2v xpair_eval(
    const f4v* __restrict__ tab4, float g,
    float px, float py, float pz, float qx, float qy, float qz)
{
  const float fx = floorf((qx + 1.f) / g);
  const float fy = floorf((qy + 1.f) / g);
  const float fz = floorf((qz + 1.f) / g);
  const float wx = (px - (fx * g - 1.f)) / g;
  const float wy = (py - (fy * g - 1.f)) / g;
  const float wz = (pz - (fz * g - 1.f)) / g;
  const u32 bx = (u32)(int)fx;
  const u32 y0 = (u32)(int)fy * P1, y1 = y0 + P1;
  const u32 z0 = (u32)(int)fz * P2, z1 = z0 + P2;
  u32 hA[4], hB[4];
  const u32 w00 = y0 ^ z0, w01 = y0 ^ z1, w10 = y1 ^ z0, w11 = y1 ^ z1;
  hA[0] = (bx ^ w00) & TABLE_MASK;  hB[0] = ((bx + 1u) ^ w00) & TABLE_MASK;
  hA[1] = (bx ^ w01) & TABLE_MASK;  hB[1] = ((bx + 1u) ^ w01) & TABLE_MASK;
  hA[2] = (bx ^ w10) & TABLE_MASK;  hB[2] = ((bx + 1u) ^ w10) & TABLE_MASK;
  hA[3] = (bx ^ w11) & TABLE_MASK;  hB[3] = ((bx + 1u) ^ w11) & TABLE_MASK;

  f4v BA[4], BB[4];
#pragma unroll
  for (int c = 0; c < 4; ++c) BA[c] = tab4[hA[c] >> 1];
#pragma unroll
  for (int c = 0; c < 4; ++c) BB[c] = BA[c];
  if (bx & 1u) {                       // divergent: only odd-bx lanes load
#pragma unroll
    for (int c = 0; c < 4; ++c) BB[c] = tab4[hB[c] >> 1];
  }
  f2v e[8];
#pragma unroll
  for (int c = 0; c < 4; ++c) {
    const bool sA = (hA[c] & 1u) != 0u;
    const bool sB = (hB[c] & 1u) != 0u;
    e[c][0]     = sA ? BA[c][2] : BA[c][0];
    e[c][1]     = sA ? BA[c][3] : BA[c][1];
    e[4 + c][0] = sB ? BB[c][2] : BB[c][0];
    e[4 + c][1] = sB ? BB[c][3] : BB[c][1];
  }
  return trilerp8(e, wx, wy, wz);
}

// dense pair-table eval: 4 aligned 16B loads (round-4 validated)
__device__ __forceinline__ f2v pair_eval(
    const f4v* __restrict__ pt, int R, float g,
    float px, float py, float pz, float qx, float qy, float qz)
{
  const float fx = floorf((qx + 1.f) / g);
  const float fy = floorf((qy + 1.f) / g);
  const float fz = floorf((qz + 1.f) / g);
  const float wx = (px - (fx * g - 1.f)) / g;
  const float wy = (py - (fy * g - 1.f)) / g;
  const float wz = (pz - (fz * g - 1.f)) / g;
  const int bx = (int)fx, by = (int)fy, bz = (int)fz;
  const int s = R + 1;
  const int base = (bx * (R + 2) + by) * s + bz;
  const f4v p00 = pt[base];
  const f4v p01 = pt[base + s];
  const f4v p10 = pt[base + (R + 2) * s];
  const f4v p11 = pt[base + (R + 3) * s];
  const float uz = 1.f - wz;
  const f2v a00 = { p00[0] * uz + p00[2] * wz, p00[1] * uz + p00[3] * wz };
  const f2v a01 = { p01[0] * uz + p01[2] * wz, p01[1] * uz + p01[3] * wz };
  const f2v a10 = { p10[0] * uz + p10[2] * wz, p10[1] * uz + p10[3] * wz };
  const f2v a11 = { p11[0] * uz + p11[2] * wz, p11[1] * uz + p11[3] * wz };
  const float uy = 1.f - wy;
  const f2v b0 = a00 * uy + a01 * wy;
  const f2v b1 = a10 * uy + a11 * wy;
  const float ux = 1.f - wx;
  return b0 * ux + b1 * wx;
}

// ---------- build dense z-pair tables for levels 0..6 (round-4 validated) ----------
__global__ __launch_bounds__(256) void rehash_kernel(
    const float* __restrict__ tables, f4v* __restrict__ pt, Params P)
{
  u32 tid = blockIdx.x * 256 + threadIdx.x;
  if (tid >= P.totE) return;
  int l = 0; u32 e = tid;
  while (e >= P.nE[l]) { e -= P.nE[l]; ++l; }
  const u32 R = (u32)P.R[l];
  const u32 vz = e % (R + 1u);
  const u32 t2 = e / (R + 1u);
  const u32 vy = t2 % (R + 2u);
  const u32 vx = t2 / (R + 2u);
  const f2v* tab = (const f2v*)tables + (size_t)l * TABLE_SIZE;
  const u32 h0 = (vx ^ (vy * P1) ^ (vz * P2)) & TABLE_MASK;
  const u32 h1 = (vx ^ (vy * P1) ^ ((vz + 1u) * P2)) & TABLE_MASK;
  const f2v a = tab[h0], b = tab[h1];
  const f4v o = { a[0], a[1], b[0], b[1] };
  pt[P.off[l] + e] = o;
}

// ---------- single-level pair pass (l5, l6), 2 pts/thread (round-4 validated) ----------
__global__ __launch_bounds__(256) void pair_pass_kernel(
    const float* __restrict__ xin, const f4v* __restrict__ pt,
    f2v* __restrict__ wsl, int npts, int strideT, int R, float g)
{
  const int n0 = blockIdx.x * 256 + threadIdx.x;
  const int n1 = n0 + strideT;
  const int c0 = n0 < npts ? n0 : npts - 1;
  const int c1 = n1 < npts ? n1 : npts - 1;
  const float px0 = xin[3 * c0 + 0], py0 = xin[3 * c0 + 1], pz0 = xin[3 * c0 + 2];
  const float px1 = xin[3 * c1 + 0], py1 = xin[3 * c1 + 1], pz1 = xin[3 * c1 + 2];
  const float qx0 = fminf(fmaxf(px0, -1.f), 1.f), qy0 = fminf(fmaxf(py0, -1.f), 1.f), qz0 = fminf(fmaxf(pz0, -1.f), 1.f);
  const float qx1 = fminf(fmaxf(px1, -1.f), 1.f), qy1 = fminf(fmaxf(py1, -1.f), 1.f), qz1 = fminf(fmaxf(pz1, -1.f), 1.f);
  const f2v r0 = pair_eval(pt, R, g, px0, py0, pz0, qx0, qy0, qz0);
  const f2v r1 = pair_eval(pt, R, g, px1, py1, pz1, qx1, qy1, qz1);
  if (n0 < npts) __builtin_nontemporal_store(r0, wsl + n0);
  if (n1 < npts) __builtin_nontemporal_store(r1, wsl + n1);
}

// ---------- hashed pass with x-pair blocks: one level, 4 pts/thread (round-7 validated) ----------
__global__ __launch_bounds__(256) void xpair_pass_kernel(
    const float* __restrict__ xin, const f4v* __restrict__ tab4,
    f2v* __restrict__ wsl, int npts, int strideT, float g)
{
  const int nb = blockIdx.x * 256 + threadIdx.x;
#pragma unroll
  for (int i = 0; i < 4; ++i) {
    const int n = nb + i * strideT;
    const int c = n < npts ? n : npts - 1;
    const float px = xin[3 * c + 0], py = xin[3 * c + 1], pz = xin[3 * c + 2];
    const float qx = fminf(fmaxf(px, -1.f), 1.f);
    const float qy = fminf(fmaxf(py, -1.f), 1.f);
    const float qz = fminf(fmaxf(pz, -1.f), 1.f);
    const f2v r = xpair_eval(tab4, g, px, py, pz, qx, qy, qz);
    if (n < npts) __builtin_nontemporal_store(r, wsl + n);
  }
}

// ---------- final: l0..l4 via z-pair tables (2.35MB, L2-resident) + ws l5..l15 +
// point-major LDS staging (r6-validated clean-FETCH structure) + coalesced out ----------
__global__ __launch_bounds__(256) void final_kernel(
    const float* __restrict__ xin, const f4v* __restrict__ pt,
    const f2v* __restrict__ ws, float* __restrict__ out, int npts, Params P)
{
  __shared__ f2v lds[NL][257];
  const int t = threadIdx.x;
  const int base = blockIdx.x * 256;
  const int n = base + t;
  const int c = n < npts ? n : npts - 1;
  {
    const float px = xin[3 * c + 0], py = xin[3 * c + 1], pz = xin[3 * c + 2];
    const float qx = fminf(fmaxf(px, -1.f), 1.f);
    const float qy = fminf(fmaxf(py, -1.f), 1.f);
    const float qz = fminf(fmaxf(pz, -1.f), 1.f);
#pragma unroll
    for (int l = 0; l < 5; ++l)
      lds[l][t] = pair_eval(pt + P.off[l], P.R[l], P.g[l], px, py, pz, qx, qy, qz);
#pragma unroll
    for (int li = 0; li < 11; ++li)
      lds[5 + li][t] = __builtin_nontemporal_load(ws + (size_t)li * npts + c);
  }
  __syncthreads();
#pragma unroll
  for (int k = 0; k < 8; ++k) {
    const int j4 = t + 256 * k;
    const int p = j4 >> 3;
    const int lp = j4 & 7;
    if (base + p < npts) {
      const f2v a = lds[2 * lp + 0][p];
      const f2v b = lds[2 * lp + 1][p];
      const f4v v = { a[0], a[1], b[0], b[1] };
      __builtin_nontemporal_store(v, (f4v*)(out + (size_t)base * 32) + j4);
    }
  }
}

// ---------- fallback: fused single-pass (round-1 validated) ----------
__global__ __launch_bounds__(256) void hash_embed_fused_kernel(
    const float* __restrict__ xin, const float* __restrict__ tables,
    float* __restrict__ out, int npts, Params P)
{
  int n = blockIdx.x * blockDim.x + threadIdx.x;
  if (n >= npts) return;
  const float px = xin[3 * n + 0], py = xin[3 * n + 1], pz = xin[3 * n + 2];
  const float qx = fminf(fmaxf(px, -1.f), 1.f);
  const float qy = fminf(fmaxf(py, -1.f), 1.f);
  const float qz = fminf(fmaxf(pz, -1.f), 1.f);
  f2v acc[NL];
#pragma unroll
  for (int l = 0; l < NL; ++l) {
    const Corners c = make_corners(P.g[l], px, py, pz, qx, qy, qz);
    const f2v* tab = (const f2v*)tables + (size_t)l * TABLE_SIZE;
    f2v e[8];
#pragma unroll
    for (int j = 0; j < 8; ++j) e[j] = tab[c.idx[j]];
    acc[l] = trilerp8(e, c.wx, c.wy, c.wz);
  }
  f4v* o = (f4v*)(out + (size_t)n * 32);
#pragma unroll
  for (int i = 0; i < 8; ++i) {
    const f4v v = { acc[2 * i][0], acc[2 * i][1], acc[2 * i + 1][0], acc[2 * i + 1][1] };
    o[i] = v;
  }
}

extern "C" void kernel_launch(void* const* d_in, const int* in_sizes, int n_in,
                              void* d_out, int out_size, void* d_ws, size_t ws_size,
                              hipStream_t stream) {
  const float* x = (const float*)d_in[0];
  const float* tables = (const float*)d_in[1];
  float* out = (float*)d_out;
  const int npts = in_sizes[0] / 3;

  Params P;
  {
    const float b = expf((logf(512.0f) - logf(16.0f)) / 15.0f);
    u32 off = 0;
    for (int l = 0; l < NL; ++l) {
      const float r = floorf(16.0f * powf(b, (float)l));
      P.g[l] = 2.0f / r;
      if (l < NPAIR) {
        const int R = (int)r;
        P.R[l] = R;
        P.nE[l] = (u32)((R + 2) * (R + 2) * (R + 1));
        P.off[l] = off;
        off += P.nE[l];
      }
    }
    P.totE = off;   // ~566K entries = ~9.06 MB of f4v
  }

  // ws layout: [l5..l15 feature slabs: 11 * npts * 8B][z-pair tables: totE * 16B]
  // Pair tables CANNOT live in d_out: final reads them while writing out.
  const size_t slab_bytes = (size_t)11 * npts * sizeof(f2v);            // 88 MB
  const size_t pt_off = (slab_bytes + 255) & ~(size_t)255;
  const size_t need = pt_off + (size_t)P.totE * sizeof(f4v);            // ~97 MB

  if (ws_size >= need) {
    f2v* ws = (f2v*)d_ws;
    f4v* pt = (f4v*)((char*)d_ws + pt_off);

    hipLaunchKernelGGL(rehash_kernel, dim3((P.totE + 255) / 256), dim3(256), 0, stream,
                       tables, pt, P);

    const int grid2 = (npts + 511) / 512;
    const int stride2 = grid2 * 256;
    for (int l = 5; l < NPAIR; ++l)
      hipLaunchKernelGGL(pair_pass_kernel, dim3(grid2), dim3(256), 0, stream,
                         x, pt + P.off[l], ws + (size_t)(l - 5) * npts, npts, stride2,
                         P.R[l], P.g[l]);

    const int grid4 = (npts + 1023) / 1024;
    const int stride4 = grid4 * 256;
    for (int l = NPAIR; l < NL; ++l)
      hipLaunchKernelGGL(xpair_pass_kernel, dim3(grid4), dim3(256), 0, stream,
                         x, (const f4v*)((const f2v*)tables + (size_t)l * TABLE_SIZE),
                         ws + (size_t)(l - 5) * npts, npts, stride4, P.g[l]);

    const int grid = (npts + 255) / 256;
    hipLaunchKernelGGL(final_kernel, dim3(grid), dim3(256), 0, stream,
                       x, pt, ws, out, npts, P);
  } else {
    hipLaunchKernelGGL(hash_embed_fused_kernel, dim3((npts + 255) / 256), dim3(256), 0, stream,
                       x, tables, out, npts, P);
  }
}